// Round 1
// baseline (14147.966 us; speedup 1.0000x reference)
//
#include <hip/hip_runtime.h>

// Seq2SeqWithAttention on MI355X.
// B=32, S=T=64, E=256, H=512, DH=1024, A=128, VT=32000.
// All recurrent math in f32; only the final (batched) logits GEMM uses bf16 MFMA.

using u16 = unsigned short;
using u32 = unsigned int;
using f32x4 = __attribute__((ext_vector_type(4))) float;
using s16x8 = __attribute__((ext_vector_type(8))) short;

__device__ __forceinline__ float sigm_(float x) { return 1.0f / (1.0f + expf(-x)); }

// round-to-nearest-even f32 -> bf16 bits
__device__ __forceinline__ u16 f2bf(float x) {
    u32 u = __float_as_uint(x);
    u += 0x7fffu + ((u >> 16) & 1u);
    return (u16)(u >> 16);
}

// ---------------- zero ----------------
__global__ __launch_bounds__(256) void k_zero(float* __restrict__ p, int n) {
    int i = blockIdx.x * 256 + threadIdx.x;
    if (i < n) p[i] = 0.0f;
}

// ---------------- embedding gather ----------------
// out[(outer*32+b)*256 + e] = emb[tok[b*64+outer]*256 + e]; 131072 threads, float4 over e
__global__ __launch_bounds__(256) void k_embed(const int* __restrict__ tok,
                                               const float* __restrict__ emb,
                                               float* __restrict__ outp) {
    int idx = blockIdx.x * 256 + threadIdx.x;   // 0..131071
    int r = idx >> 6, e4 = idx & 63;
    int outer = r >> 5, b = r & 31;
    int tk = tok[b * 64 + outer];
    ((f32x4*)outp)[(size_t)r * 64 + e4] = ((const f32x4*)emb)[(size_t)tk * 64 + e4];
}

// ---------------- generic f32 GEMM: C[M,N] = A[M,K] @ W[N,K]^T + b1 + b2 ----------------
// 64x64 tile, 256 threads, 4x4 per thread, BK=16.
__global__ __launch_bounds__(256) void k_gemm_f32(
    const float* __restrict__ Am, int lda,
    const float* __restrict__ Wm, int ldw,
    const float* __restrict__ b1, const float* __restrict__ b2,
    float* __restrict__ C, int ldc, int M, int N, int K)
{
    __shared__ float As[16][65];
    __shared__ float Ws[16][65];
    int tid = threadIdx.x;
    int bm = blockIdx.y * 64, bn = blockIdx.x * 64;
    int tm = (tid >> 4) << 2, tn = (tid & 15) << 2;
    float acc[4][4] = {};
    int m = tid >> 4, kk = tid & 15;
    for (int k0 = 0; k0 < K; k0 += 16) {
#pragma unroll
        for (int rr = 0; rr < 4; ++rr)
            As[kk][m + rr * 16] = Am[(size_t)(bm + m + rr * 16) * lda + k0 + kk];
#pragma unroll
        for (int rr = 0; rr < 4; ++rr)
            Ws[kk][m + rr * 16] = Wm[(size_t)(bn + m + rr * 16) * ldw + k0 + kk];
        __syncthreads();
#pragma unroll
        for (int k2 = 0; k2 < 16; ++k2) {
            float av[4], wv[4];
#pragma unroll
            for (int x = 0; x < 4; ++x) { av[x] = As[k2][tm + x]; wv[x] = Ws[k2][tn + x]; }
#pragma unroll
            for (int i = 0; i < 4; ++i)
#pragma unroll
                for (int j = 0; j < 4; ++j) acc[i][j] += av[i] * wv[j];
        }
        __syncthreads();
    }
#pragma unroll
    for (int i = 0; i < 4; ++i) {
        int mm = bm + tm + i; if (mm >= M) continue;
#pragma unroll
        for (int j = 0; j < 4; ++j) {
            int nn = bn + tn + j; if (nn >= N) continue;
            float v = acc[i][j];
            if (b1) v += b1[nn];
            if (b2) v += b2[nn];
            C[(size_t)mm * ldc + nn] = v;
        }
    }
}

// ---------------- encoder step (both directions, one gate per thread) ----------------
// grid 512 blocks x 256 thr: dir = blk>>8; j = ((blk&255)<<1)|(tid>>7); gate=(tid>>5)&3; b=tid&31
__global__ __launch_bounds__(256) void k_enc_step(
    const float* __restrict__ Gf, const float* __restrict__ Gb,
    const float* __restrict__ Whh_f, const float* __restrict__ Whh_b,
    const float* __restrict__ hin_f, const float* __restrict__ hin_b,
    float* __restrict__ hout_f, float* __restrict__ hout_b,
    float* __restrict__ c_f, float* __restrict__ c_b,
    float* __restrict__ enc_out, int step)
{
    int tid = threadIdx.x;
    int b = tid & 31, gate = (tid >> 5) & 3, jloc = tid >> 7;
    int blk = blockIdx.x;
    int dir = blk >> 8;
    int j = ((blk & 255) << 1) | jloc;
    int t = dir ? (63 - step) : step;
    const float* G  = dir ? Gb : Gf;
    const float* W  = (dir ? Whh_b : Whh_f) + (size_t)(gate * 512 + j) * 512;
    const float* hb = (dir ? hin_b : hin_f) + b * 512;
    float acc = G[((size_t)t * 32 + b) * 2048 + gate * 512 + j];
#pragma unroll 4
    for (int k = 0; k < 512; k += 4) {
        f32x4 w4 = *(const f32x4*)(W + k);
        f32x4 h4 = *(const f32x4*)(hb + k);
        acc += w4.x * h4.x + w4.y * h4.y + w4.z * h4.z + w4.w * h4.w;
    }
    __shared__ float red[2][4][32];
    red[jloc][gate][b] = acc;
    __syncthreads();
    if (gate == 0) {
        float gi = red[jloc][0][b], gf = red[jloc][1][b];
        float gg = red[jloc][2][b], go = red[jloc][3][b];
        float* cp = (dir ? c_b : c_f) + b * 512 + j;
        float cn = sigm_(gf) * cp[0] + sigm_(gi) * tanhf(gg);
        cp[0] = cn;
        float hn = sigm_(go) * tanhf(cn);
        (dir ? hout_b : hout_f)[b * 512 + j] = hn;
        enc_out[((size_t)b * 64 + t) * 1024 + dir * 512 + j] = hn;
    }
}

// ---------------- decoder init: h0/c0 = concat(enc finals) ----------------
__global__ __launch_bounds__(256) void k_dec_init(
    const float* __restrict__ hf, const float* __restrict__ hb,
    const float* __restrict__ cf, const float* __restrict__ cb,
    float* __restrict__ hd0, float* __restrict__ cd)
{
    int idx = blockIdx.x * 256 + threadIdx.x;   // 0..32767
    int b = idx >> 10, j = idx & 1023;
    hd0[idx] = (j < 512) ? hf[b * 512 + j] : hb[b * 512 + (j - 512)];
    cd[idx]  = (j < 512) ? cf[b * 512 + j] : cb[b * 512 + (j - 512)];
}

// ---------------- attention step: one block per batch row ----------------
__global__ __launch_bounds__(256) void k_attn(
    const float* __restrict__ hd, const float* __restrict__ Wd, const float* __restrict__ bd,
    const float* __restrict__ eproj, const float* __restrict__ v_att, const float* __restrict__ bv,
    const float* __restrict__ enc_out, float* __restrict__ ctx, u16* __restrict__ Abf, int t)
{
    int b = blockIdx.x, tid = threadIdx.x;
    __shared__ __align__(16) float sh[1024];
    __shared__ float red[256];
    __shared__ float dp[128];
    __shared__ float sc[64];
    for (int i = tid; i < 1024; i += 256) sh[i] = hd[b * 1024 + i];
    __syncthreads();
    {   // dproj = h @ Wd^T + bd  (two half-K partials per a)
        int a = tid & 127, half = tid >> 7;
        const float* wr = Wd + (size_t)a * 1024 + half * 512;
        const float* hh = sh + half * 512;
        float s = 0.0f;
        for (int k = 0; k < 512; k += 4) {
            f32x4 w4 = *(const f32x4*)(wr + k);
            f32x4 h4 = *(const f32x4*)(hh + k);
            s += w4.x * h4.x + w4.y * h4.y + w4.z * h4.z + w4.w * h4.w;
        }
        red[tid] = s;
    }
    __syncthreads();
    if (tid < 128) dp[tid] = red[tid] + red[tid + 128] + bd[tid];
    __syncthreads();
    {   // scores[s] = sum_a v[a]*tanh(dp[a]+eproj[b,s,a]) + bv
        int si = tid >> 2, q = tid & 3;
        const float* ep = eproj + ((size_t)b * 64 + si) * 128 + q * 32;
        float s = 0.0f;
#pragma unroll 8
        for (int a = 0; a < 32; ++a) s += v_att[q * 32 + a] * tanhf(dp[q * 32 + a] + ep[a]);
        red[tid] = s;
    }
    __syncthreads();
    if (tid < 64)
        sc[tid] = red[tid * 4] + red[tid * 4 + 1] + red[tid * 4 + 2] + red[tid * 4 + 3] + bv[0];
    __syncthreads();
    if (tid < 64) {   // softmax over S=64 inside wave 0
        float x = sc[tid], mx = x;
#pragma unroll
        for (int off = 32; off; off >>= 1) mx = fmaxf(mx, __shfl_xor(mx, off));
        float e = expf(x - mx), ssum = e;
#pragma unroll
        for (int off = 32; off; off >>= 1) ssum += __shfl_xor(ssum, off);
        sc[tid] = e / ssum;
    }
    __syncthreads();
    // ctx[b,j] = sum_s w[s]*enc_out[b,s,j]
    float c0 = 0, c1 = 0, c2 = 0, c3 = 0;
    const float* eo = enc_out + (size_t)b * 64 * 1024;
    for (int s2 = 0; s2 < 64; ++s2) {
        float w = sc[s2];
        const float* rowp = eo + s2 * 1024;
        c0 += w * rowp[tid];       c1 += w * rowp[tid + 256];
        c2 += w * rowp[tid + 512]; c3 += w * rowp[tid + 768];
    }
    float* cb2 = ctx + b * 1024;
    cb2[tid] = c0; cb2[tid + 256] = c1; cb2[tid + 512] = c2; cb2[tid + 768] = c3;
    u16* ar = Abf + ((size_t)t * 32 + b) * 2048 + 1024;
    ar[tid] = f2bf(c0); ar[tid + 256] = f2bf(c1);
    ar[tid + 512] = f2bf(c2); ar[tid + 768] = f2bf(c3);
}

// ---------------- decoder LSTM gates + pointwise ----------------
// grid 512 x 256: j = (blk<<1)|(tid>>7); gate=(tid>>5)&3; b=tid&31; K = 1024(h) + 1024(ctx)
__global__ __launch_bounds__(256) void k_dec_gates(
    const float* __restrict__ Pre, const float* __restrict__ Whh, const float* __restrict__ Wih,
    const float* __restrict__ hin, const float* __restrict__ ctx,
    float* __restrict__ hout, float* __restrict__ cd, u16* __restrict__ Abf, int t)
{
    int tid = threadIdx.x;
    int b = tid & 31, gate = (tid >> 5) & 3, jloc = tid >> 7;
    int j = (blockIdx.x << 1) | jloc;
    float acc = Pre[((size_t)t * 32 + b) * 4096 + gate * 1024 + j];
    {
        const float* wr = Whh + (size_t)(gate * 1024 + j) * 1024;
        const float* hb = hin + b * 1024;
#pragma unroll 4
        for (int k = 0; k < 1024; k += 4) {
            f32x4 w4 = *(const f32x4*)(wr + k);
            f32x4 h4 = *(const f32x4*)(hb + k);
            acc += w4.x * h4.x + w4.y * h4.y + w4.z * h4.z + w4.w * h4.w;
        }
    }
    {
        const float* wr = Wih + (size_t)(gate * 1024 + j) * 1280 + 256;  // ctx part of dec_Wih
        const float* cb2 = ctx + b * 1024;
#pragma unroll 4
        for (int k = 0; k < 1024; k += 4) {
            f32x4 w4 = *(const f32x4*)(wr + k);
            f32x4 h4 = *(const f32x4*)(cb2 + k);
            acc += w4.x * h4.x + w4.y * h4.y + w4.z * h4.z + w4.w * h4.w;
        }
    }
    __shared__ float red[2][4][32];
    red[jloc][gate][b] = acc;
    __syncthreads();
    if (gate == 0) {
        float gi = red[jloc][0][b], gf = red[jloc][1][b];
        float gg = red[jloc][2][b], go = red[jloc][3][b];
        int idx = b * 1024 + j;
        float cn = sigm_(gf) * cd[idx] + sigm_(gi) * tanhf(gg);
        cd[idx] = cn;
        float hn = sigm_(go) * tanhf(cn);
        hout[idx] = hn;
        Abf[((size_t)t * 32 + b) * 2048 + j] = f2bf(hn);
    }
}

// ---------------- f32 -> bf16 cast (Wo) ----------------
__global__ __launch_bounds__(256) void k_cast_bf16(const float* __restrict__ in,
                                                   u16* __restrict__ outp, int n8) {
    int idx = blockIdx.x * 256 + threadIdx.x;
    if (idx >= n8) return;
    const f32x4* p = (const f32x4*)in + (size_t)idx * 2;
    f32x4 a = p[0], c = p[1];
    u32 r0 = (u32)f2bf(a.x) | ((u32)f2bf(a.y) << 16);
    u32 r1 = (u32)f2bf(a.z) | ((u32)f2bf(a.w) << 16);
    u32 r2 = (u32)f2bf(c.x) | ((u32)f2bf(c.y) << 16);
    u32 r3 = (u32)f2bf(c.z) | ((u32)f2bf(c.w) << 16);
    u32* o = (u32*)(outp + (size_t)idx * 8);
    o[0] = r0; o[1] = r1; o[2] = r2; o[3] = r3;
}

// ---------------- logits GEMM: out = A[2048,2048]bf16 @ Wo[32000,2048]bf16^T + bo ----------------
// m97 structure: 128x128 tile, 4 waves x (64x64), BK=32, global_load_lds width 16.
#define GLL(g, l) __builtin_amdgcn_global_load_lds( \
    (__attribute__((address_space(1))) void*)(g),   \
    (__attribute__((address_space(3))) void*)(l), 16, 0, 0)

__global__ __launch_bounds__(256) void k_logits(
    const u16* __restrict__ Abf, const u16* __restrict__ Wbf,
    const float* __restrict__ bo, float* __restrict__ outp)
{
    __shared__ __align__(16) u16 As[128 * 32];
    __shared__ __align__(16) u16 Bs[128 * 32];
    int tid = threadIdx.x;
    int wave = tid >> 6, lane = tid & 63;
    int bm = blockIdx.y * 128, bn = blockIdx.x * 128;
    int wm = wave & 1, wn = wave >> 1;
    f32x4 acc[4][4] = {};

    // staging: wave covers rows [wave*32, wave*32+32); issue q adds 16 rows
    int rA = wave * 32 + (lane >> 2);
    int cb2 = (lane & 3) * 16;                        // byte col within 64B row
    const char* gA  = (const char*)Abf + (size_t)(bm + rA) * 4096 + cb2;
    const char* gA1 = gA + 16 * 4096;
    const char* gB  = (const char*)Wbf + (size_t)(bn + rA) * 4096 + cb2;
    const char* gB1 = gB + 16 * 4096;
    char* lA = (char*)As + wave * 2048;
    char* lB = (char*)Bs + wave * 2048;
    const u16* rdA = As + (wm * 64 + (lane & 15)) * 32 + (lane >> 4) * 8;
    const u16* rdB = Bs + (wn * 64 + (lane & 15)) * 32 + (lane >> 4) * 8;

    for (int k0 = 0; k0 < 2048; k0 += 32) {
        int kb = k0 * 2;
        GLL(gA + kb, lA);
        GLL(gA1 + kb, lA + 1024);
        GLL(gB + kb, lB);
        GLL(gB1 + kb, lB + 1024);
        __syncthreads();                 // drains vmcnt -> LDS filled
        s16x8 af[4], bf[4];
#pragma unroll
        for (int m2 = 0; m2 < 4; ++m2) af[m2] = *(const s16x8*)(rdA + m2 * 512);
#pragma unroll
        for (int n2 = 0; n2 < 4; ++n2) bf[n2] = *(const s16x8*)(rdB + n2 * 512);
#pragma unroll
        for (int m2 = 0; m2 < 4; ++m2)
#pragma unroll
            for (int n2 = 0; n2 < 4; ++n2)
                acc[m2][n2] = __builtin_amdgcn_mfma_f32_16x16x32_bf16(
                    af[m2], bf[n2], acc[m2][n2], 0, 0, 0);
        __syncthreads();                 // protect LDS before next-stage overwrite
    }

    // epilogue: C/D layout col=lane&15, row=(lane>>4)*4+reg; remap row (t*32+b) -> out[b*64+t]
    int rbase = bm + wm * 64 + ((lane >> 4) << 2);
    int cbase = bn + wn * 64 + (lane & 15);
#pragma unroll
    for (int n2 = 0; n2 < 4; ++n2) {
        int col = cbase + n2 * 16;
        float bias = bo[col];
#pragma unroll
        for (int m2 = 0; m2 < 4; ++m2) {
            f32x4 v = acc[m2][n2];
#pragma unroll
            for (int jj = 0; jj < 4; ++jj) {
                int row = rbase + m2 * 16 + jj;
                int tt = row >> 5, bb = row & 31;
                outp[((size_t)(bb * 64 + tt)) * 32000 + col] = v[jj] + bias;
            }
        }
    }
}

// ---------------- host ----------------
extern "C" void kernel_launch(void* const* d_in, const int* in_sizes, int n_in,
                              void* d_out, int out_size, void* d_ws, size_t ws_size,
                              hipStream_t stream)
{
    (void)in_sizes; (void)n_in; (void)out_size; (void)ws_size;
    const int*   src     = (const int*)d_in[0];
    const int*   tgt     = (const int*)d_in[1];
    const float* enc_emb = (const float*)d_in[2];
    const float* eWih_f  = (const float*)d_in[3];
    const float* eWhh_f  = (const float*)d_in[4];
    const float* ebih_f  = (const float*)d_in[5];
    const float* ebhh_f  = (const float*)d_in[6];
    const float* eWih_b  = (const float*)d_in[7];
    const float* eWhh_b  = (const float*)d_in[8];
    const float* ebih_b  = (const float*)d_in[9];
    const float* ebhh_b  = (const float*)d_in[10];
    const float* dec_emb = (const float*)d_in[11];
    const float* Wd      = (const float*)d_in[12];
    const float* bd      = (const float*)d_in[13];
    const float* We      = (const float*)d_in[14];
    const float* be      = (const float*)d_in[15];
    const float* v_att   = (const float*)d_in[16];
    const float* bv      = (const float*)d_in[17];
    const float* dWih    = (const float*)d_in[18];
    const float* dWhh    = (const float*)d_in[19];
    const float* dbih    = (const float*)d_in[20];
    const float* dbhh    = (const float*)d_in[21];
    const float* Wo      = (const float*)d_in[22];
    const float* bo      = (const float*)d_in[23];
    float* out = (float*)d_out;

    char* w = (char*)d_ws;
    auto alloc = [&](size_t nbytes) -> void* {
        void* p = (void*)w;
        w += (nbytes + 255) & ~(size_t)255;
        return p;
    };
    float* Xe      = (float*)alloc(524288u * 4);      // [S*B, E]
    float* Gf      = (float*)alloc(4194304u * 4);     // [S*B, 4H]
    float* Gb      = (float*)alloc(4194304u * 4);
    float* st      = (float*)alloc(98304u * 4);       // hf0,hf1,hb0,hb1,cf,cb (16384 each)
    float* hf[2]   = { st, st + 16384 };
    float* hb[2]   = { st + 32768, st + 49152 };
    float* cf      = st + 65536;
    float* cbu     = st + 81920;
    float* enc_out = (float*)alloc(2097152u * 4);     // [B,S,DH]
    float* eproj   = (float*)alloc(262144u * 4);      // [B,S,A]
    float* Ed      = (float*)alloc(524288u * 4);      // [T*B, E]
    float* Pre     = (float*)alloc(8388608u * 4);     // [T*B, 4DH]
    float* dst     = (float*)alloc(131072u * 4);      // hd0,hd1,cd,ctx (32768 each)
    float* hd[2]   = { dst, dst + 32768 };
    float* cd      = dst + 65536;
    float* ctxb    = dst + 98304;
    u16*   Abf     = (u16*)alloc(4194304u * 2);       // [T*B, 2DH] bf16
    u16*   Wbf     = (u16*)alloc(65536000u * 2);      // [VT, 2DH] bf16

    k_zero<<<384, 256, 0, stream>>>(st, 98304);
    k_cast_bf16<<<32000, 256, 0, stream>>>(Wo, Wbf, 8192000);
    k_embed<<<512, 256, 0, stream>>>(src, enc_emb, Xe);
    k_embed<<<512, 256, 0, stream>>>(tgt, dec_emb, Ed);

    dim3 g1(32, 32);   // N=2048, M=2048
    k_gemm_f32<<<g1, 256, 0, stream>>>(Xe, 256, eWih_f, 256, ebih_f, ebhh_f, Gf, 2048, 2048, 2048, 256);
    k_gemm_f32<<<g1, 256, 0, stream>>>(Xe, 256, eWih_b, 256, ebih_b, ebhh_b, Gb, 2048, 2048, 2048, 256);
    dim3 g2(64, 32);   // N=4096, M=2048
    k_gemm_f32<<<g2, 256, 0, stream>>>(Ed, 256, dWih, 1280, dbih, dbhh, Pre, 4096, 2048, 4096, 256);

    for (int s = 0; s < 64; ++s) {
        int i0 = s & 1, i1 = 1 - i0;
        k_enc_step<<<512, 256, 0, stream>>>(Gf, Gb, eWhh_f, eWhh_b,
                                            hf[i0], hb[i0], hf[i1], hb[i1],
                                            cf, cbu, enc_out, s);
    }

    dim3 g3(2, 32);    // N=128, M=2048
    k_gemm_f32<<<g3, 256, 0, stream>>>(enc_out, 1024, We, 1024, be, nullptr, eproj, 128, 2048, 128, 1024);
    k_dec_init<<<128, 256, 0, stream>>>(hf[0], hb[0], cf, cbu, hd[0], cd);

    for (int t = 0; t < 64; ++t) {
        int i0 = t & 1, i1 = 1 - i0;
        k_attn<<<32, 256, 0, stream>>>(hd[i0], Wd, bd, eproj, v_att, bv, enc_out, ctxb, Abf, t);
        k_dec_gates<<<512, 256, 0, stream>>>(Pre, dWhh, dWih, hd[i0], ctxb, hd[i1], cd, Abf, t);
    }

    dim3 g4(250, 16);  // N=32000/128, M=2048/128
    k_logits<<<g4, 256, 0, stream>>>(Abf, Wbf, bo, out);
}

// Round 2
// 3594.042 us; speedup vs baseline: 3.9365x; 3.9365x over previous
//
#include <hip/hip_runtime.h>

// Seq2SeqWithAttention on MI355X. B=32, S=T=64, E=256, H=512, DH=1024, A=128, VT=32000.
// R2: MFMA everywhere. Recurrent-step kernels stream bf16 weights (gate-interleaved
// rows n=j*4+g) straight from global into MFMA fragments; f32 cell state.

using u16 = unsigned short;
using u32 = unsigned int;
using f32x4 = __attribute__((ext_vector_type(4))) float;
using s16x8 = __attribute__((ext_vector_type(8))) short;

__device__ __forceinline__ float sigm_(float x) { return 1.0f / (1.0f + expf(-x)); }

__device__ __forceinline__ u16 f2bf(float x) {
    u32 u = __float_as_uint(x);
    u += 0x7fffu + ((u >> 16) & 1u);
    return (u16)(u >> 16);
}
__device__ __forceinline__ u32 pk2(float a, float b) {
    return (u32)f2bf(a) | ((u32)f2bf(b) << 16);
}

// ---------------- zero ----------------
__global__ __launch_bounds__(256) void k_zero(float* __restrict__ p, int n) {
    int i = blockIdx.x * 256 + threadIdx.x;
    if (i < n) p[i] = 0.0f;
}

// ---------------- f32 -> bf16 cast ----------------
__global__ __launch_bounds__(256) void k_cast_bf16(const float* __restrict__ in,
                                                   u16* __restrict__ outp, int n8) {
    int idx = blockIdx.x * 256 + threadIdx.x;
    if (idx >= n8) return;
    const f32x4* p = (const f32x4*)in + (size_t)idx * 2;
    f32x4 a = p[0], c = p[1];
    u32* o = (u32*)(outp + (size_t)idx * 8);
    o[0] = pk2(a.x, a.y); o[1] = pk2(a.z, a.w);
    o[2] = pk2(c.x, c.y); o[3] = pk2(c.z, c.w);
}

// ---------------- embedding gather -> bf16 [pos*32+b][256] ----------------
__global__ __launch_bounds__(256) void k_embed_bf(const int* __restrict__ tok,
                                                  const float* __restrict__ emb,
                                                  u16* __restrict__ outp) {
    int idx = blockIdx.x * 256 + threadIdx.x;   // 0..131071
    int r = idx >> 6, e4 = idx & 63;
    int outer = r >> 5, b = r & 31;
    int tk = tok[b * 64 + outer];
    f32x4 v = ((const f32x4*)emb)[(size_t)tk * 64 + e4];
    u32* o = (u32*)(outp + (size_t)r * 256 + (e4 << 2));
    o[0] = pk2(v.x, v.y); o[1] = pk2(v.z, v.w);
}

// ---------------- weight prep: gate-interleaved bf16 rows ----------------
// dst[n][k] = bf16(src[(n&3)*J + (n>>2)][srcOff + k]); 4 k per thread.
__global__ __launch_bounds__(256) void k_prep_perm(
    const float* __restrict__ src, u16* __restrict__ dst,
    int J, int K4, int srcStride, int srcOff, int total)
{
    int idx = blockIdx.x * 256 + threadIdx.x;
    if (idx >= total) return;
    int n = idx / K4, kq = (idx - n * K4) << 2;
    int orig = (n & 3) * J + (n >> 2);
    f32x4 v = *(const f32x4*)(src + (size_t)orig * srcStride + srcOff + kq);
    u32* o = (u32*)(dst + (size_t)n * (K4 << 2) + kq);
    o[0] = pk2(v.x, v.y); o[1] = pk2(v.z, v.w);
}

// dec W2[n][k]: k<1024 -> dWhh[orig][k]; k>=1024 -> dWih[orig][256+k-1024]. orig=(n&3)*1024+(n>>2)
__global__ __launch_bounds__(256) void k_prep_w2(
    const float* __restrict__ Whh, const float* __restrict__ Wih, u16* __restrict__ dst)
{
    int idx = blockIdx.x * 256 + threadIdx.x;   // total 2,097,152
    int n = idx >> 9, kq = (idx & 511) << 2;
    int orig = (n & 3) * 1024 + (n >> 2);
    const float* s = (kq < 1024) ? (Whh + (size_t)orig * 1024 + kq)
                                 : (Wih + (size_t)orig * 1280 + 256 + (kq - 1024));
    f32x4 v = *(const f32x4*)s;
    u32* o = (u32*)(dst + (size_t)n * 2048 + kq);
    o[0] = pk2(v.x, v.y); o[1] = pk2(v.z, v.w);
}

// ---------------- generic bf16 MFMA GEMM (m97 structure, 128x128 tile, BK=32) ----------------
// C_f32[M,N] = A_bf[M,K] @ B_bf[N,K]^T (+ bias at orig col). 1D grid nM*nN, XCD-swizzled,
// m-tile fastest so consecutive blocks (same XCD) share the B panel (L2 reuse).
#define GLL(g, l) __builtin_amdgcn_global_load_lds( \
    (__attribute__((address_space(1))) void*)(g),   \
    (__attribute__((address_space(3))) void*)(l), 16, 0, 0)

__global__ __launch_bounds__(256) void k_gemm_bf(
    const u16* __restrict__ A, const u16* __restrict__ B, int K,
    const float* __restrict__ b1, const float* __restrict__ b2, int biasJ,
    float* __restrict__ C, int ldc, int nM, int nN, int remapOut, int swz)
{
    __shared__ __align__(16) u16 As[128 * 32];
    __shared__ __align__(16) u16 Bs[128 * 32];
    int w = blockIdx.x;
    if (swz) { int cpx = (nM * nN) >> 3; w = (w & 7) * cpx + (w >> 3); }
    int bm = (w % nM) * 128, bn = (w / nM) * 128;
    int tid = threadIdx.x, wave = tid >> 6, lane = tid & 63;
    int wm = wave & 1, wn = wave >> 1;
    f32x4 acc[4][4] = {};

    int rA = wave * 32 + (lane >> 2);
    int cb2 = (lane & 3) * 16;
    const char* gA = (const char*)A + ((size_t)(bm + rA) * K) * 2 + cb2;
    const char* gB = (const char*)B + ((size_t)(bn + rA) * K) * 2 + cb2;
    size_t rowskip = (size_t)16 * K * 2;
    char* lA = (char*)As + wave * 2048;
    char* lB = (char*)Bs + wave * 2048;
    const u16* rdA = As + (wm * 64 + (lane & 15)) * 32 + (lane >> 4) * 8;
    const u16* rdB = Bs + (wn * 64 + (lane & 15)) * 32 + (lane >> 4) * 8;

    for (int k0 = 0; k0 < K; k0 += 32) {
        size_t kb = (size_t)k0 * 2;
        GLL(gA + kb, lA); GLL(gA + kb + rowskip, lA + 1024);
        GLL(gB + kb, lB); GLL(gB + kb + rowskip, lB + 1024);
        __syncthreads();
        s16x8 af[4], bfv[4];
#pragma unroll
        for (int m2 = 0; m2 < 4; ++m2) af[m2] = *(const s16x8*)(rdA + m2 * 512);
#pragma unroll
        for (int n2 = 0; n2 < 4; ++n2) bfv[n2] = *(const s16x8*)(rdB + n2 * 512);
#pragma unroll
        for (int m2 = 0; m2 < 4; ++m2)
#pragma unroll
            for (int n2 = 0; n2 < 4; ++n2)
                acc[m2][n2] = __builtin_amdgcn_mfma_f32_16x16x32_bf16(
                    af[m2], bfv[n2], acc[m2][n2], 0, 0, 0);
        __syncthreads();
    }

    int rbase = bm + wm * 64 + ((lane >> 4) << 2);
    int cbase = bn + wn * 64 + (lane & 15);
#pragma unroll
    for (int n2 = 0; n2 < 4; ++n2) {
        int col = cbase + n2 * 16;
        int bcol = biasJ ? ((col & 3) * biasJ + (col >> 2)) : col;
        float bias = (b1 ? b1[bcol] : 0.0f) + (b2 ? b2[bcol] : 0.0f);
#pragma unroll
        for (int m2 = 0; m2 < 4; ++m2) {
            f32x4 v = acc[m2][n2];
#pragma unroll
            for (int jj = 0; jj < 4; ++jj) {
                int row = rbase + m2 * 16 + jj;
                int orow = remapOut ? ((row & 31) * 64 + (row >> 5)) : row;
                C[(size_t)orow * ldc + col] = v[jj] + bias;
            }
        }
    }
}

// ---------------- encoder step (MFMA, both dirs) ----------------
// 128 blocks x 256 thr: dir=blk>>6, n0=(blk&63)*32 within dir (N=2048 gate-interleaved).
// Wave: N-sub 16 (w>>1), K-half 256 (w&1). Pointwise: 32b x 8j.
__global__ __launch_bounds__(256) void k_enc_step2(
    const u16* __restrict__ Wef, const u16* __restrict__ Web,
    const float* __restrict__ Gfp, const float* __restrict__ Gbp,
    const u16* __restrict__ hA, u16* __restrict__ hB,
    float* __restrict__ cf, float* __restrict__ cb,
    float* __restrict__ enc_out, u16* __restrict__ enc_out_bf, int step)
{
    int tid = threadIdx.x, lane = tid & 63, w = tid >> 6;
    int dir = blockIdx.x >> 6, nb = blockIdx.x & 63;
    int n0 = nb * 32;
    int cn = (w >> 1) << 4, kh = w & 1;
    const u16* W = dir ? Web : Wef;
    const u16* Ab = hA + dir * 16384;
    const u16* Bp  = W + (size_t)(n0 + cn + (lane & 15)) * 512 + kh * 256 + ((lane >> 4) << 3);
    const u16* Ap0 = Ab + (size_t)(lane & 15) * 512 + kh * 256 + ((lane >> 4) << 3);
    const u16* Ap1 = Ap0 + 16 * 512;
    f32x4 acc0 = {}, acc1 = {};
#pragma unroll
    for (int it = 0; it < 8; ++it) {
        s16x8 bfr = *(const s16x8*)(Bp + it * 32);
        s16x8 a0  = *(const s16x8*)(Ap0 + it * 32);
        s16x8 a1  = *(const s16x8*)(Ap1 + it * 32);
        acc0 = __builtin_amdgcn_mfma_f32_16x16x32_bf16(a0, bfr, acc0, 0, 0, 0);
        acc1 = __builtin_amdgcn_mfma_f32_16x16x32_bf16(a1, bfr, acc1, 0, 0, 0);
    }
    __shared__ float sacc[2][32][33];
    int cl = cn + (lane & 15), r0 = (lane >> 4) << 2;
#pragma unroll
    for (int r = 0; r < 4; ++r) {
        sacc[kh][r0 + r][cl] = acc0[r];
        sacc[kh][16 + r0 + r][cl] = acc1[r];
    }
    __syncthreads();
    int b = tid >> 3, jl = tid & 7;
    int j = (n0 >> 2) + jl;
    int t = dir ? (63 - step) : step;
    const float* Gp = dir ? Gbp : Gfp;
    f32x4 p4 = *(const f32x4*)(Gp + ((size_t)(t * 32 + b)) * 2048 + n0 + (jl << 2));
    int c4 = jl << 2;
    float gi = sacc[0][b][c4 + 0] + sacc[1][b][c4 + 0] + p4.x;
    float gf = sacc[0][b][c4 + 1] + sacc[1][b][c4 + 1] + p4.y;
    float gg = sacc[0][b][c4 + 2] + sacc[1][b][c4 + 2] + p4.z;
    float go = sacc[0][b][c4 + 3] + sacc[1][b][c4 + 3] + p4.w;
    float* cp = (dir ? cb : cf) + b * 512 + j;
    float cnew = sigm_(gf) * cp[0] + sigm_(gi) * tanhf(gg);
    cp[0] = cnew;
    float h = sigm_(go) * tanhf(cnew);
    size_t eo = ((size_t)(b * 64 + t)) * 1024 + dir * 512 + j;
    enc_out[eo] = h;
    enc_out_bf[eo] = f2bf(h);
    hB[dir * 16384 + b * 512 + j] = f2bf(h);
}

// ---------------- decoder gates step (MFMA) ----------------
// 128 blocks x 256: n0=blk*32 (N=4096 gate-interleaved), K=2048 over hc=[h|ctx] bf16.
__global__ __launch_bounds__(256) void k_dec_step(
    const u16* __restrict__ W2, const float* __restrict__ Prep,
    const u16* __restrict__ hcA, u16* __restrict__ hcB,
    float* __restrict__ hd_out, float* __restrict__ cd,
    u16* __restrict__ Abf, int t)
{
    int tid = threadIdx.x, lane = tid & 63, w = tid >> 6;
    int n0 = blockIdx.x * 32;
    int cn = (w >> 1) << 4, kh = w & 1;
    const u16* Bp  = W2 + (size_t)(n0 + cn + (lane & 15)) * 2048 + kh * 1024 + ((lane >> 4) << 3);
    const u16* Ap0 = hcA + (size_t)(lane & 15) * 2048 + kh * 1024 + ((lane >> 4) << 3);
    const u16* Ap1 = Ap0 + 16 * 2048;
    f32x4 acc0 = {}, acc1 = {};
#pragma unroll 4
    for (int it = 0; it < 32; ++it) {
        s16x8 bfr = *(const s16x8*)(Bp + it * 32);
        s16x8 a0  = *(const s16x8*)(Ap0 + it * 32);
        s16x8 a1  = *(const s16x8*)(Ap1 + it * 32);
        acc0 = __builtin_amdgcn_mfma_f32_16x16x32_bf16(a0, bfr, acc0, 0, 0, 0);
        acc1 = __builtin_amdgcn_mfma_f32_16x16x32_bf16(a1, bfr, acc1, 0, 0, 0);
    }
    __shared__ float sacc[2][32][33];
    int cl = cn + (lane & 15), r0 = (lane >> 4) << 2;
#pragma unroll
    for (int r = 0; r < 4; ++r) {
        sacc[kh][r0 + r][cl] = acc0[r];
        sacc[kh][16 + r0 + r][cl] = acc1[r];
    }
    __syncthreads();
    int b = tid >> 3, jl = tid & 7;
    int j = (n0 >> 2) + jl;
    f32x4 p4 = *(const f32x4*)(Prep + ((size_t)(t * 32 + b)) * 4096 + n0 + (jl << 2));
    int c4 = jl << 2;
    float gi = sacc[0][b][c4 + 0] + sacc[1][b][c4 + 0] + p4.x;
    float gf = sacc[0][b][c4 + 1] + sacc[1][b][c4 + 1] + p4.y;
    float gg = sacc[0][b][c4 + 2] + sacc[1][b][c4 + 2] + p4.z;
    float go = sacc[0][b][c4 + 3] + sacc[1][b][c4 + 3] + p4.w;
    int ci = b * 1024 + j;
    float cnew = sigm_(gf) * cd[ci] + sigm_(gi) * tanhf(gg);
    cd[ci] = cnew;
    float h = sigm_(go) * tanhf(cnew);
    hd_out[ci] = h;
    u16 hb = f2bf(h);
    hcB[(size_t)b * 2048 + j] = hb;
    Abf[((size_t)(t * 32 + b)) * 2048 + j] = hb;
}

// ---------------- decoder init ----------------
__global__ __launch_bounds__(256) void k_dec_init(
    const float* __restrict__ enc_out, const float* __restrict__ cf, const float* __restrict__ cb,
    float* __restrict__ hd0, float* __restrict__ cd, u16* __restrict__ hc0)
{
    int idx = blockIdx.x * 256 + threadIdx.x;   // 0..32767
    int b = idx >> 10, j = idx & 1023;
    float hv = (j < 512) ? enc_out[((size_t)(b * 64 + 63)) * 1024 + j]
                         : enc_out[((size_t)(b * 64 + 0)) * 1024 + j];
    float cv = (j < 512) ? cf[b * 512 + j] : cb[b * 512 + (j - 512)];
    hd0[idx] = hv;
    cd[idx] = cv;
    hc0[(size_t)b * 2048 + j] = f2bf(hv);
}

// ---------------- attention step ----------------
__global__ __launch_bounds__(256) void k_attn(
    const float* __restrict__ hd, const float* __restrict__ Wd, const float* __restrict__ bd,
    const float* __restrict__ eproj, const float* __restrict__ v_att, const float* __restrict__ bv,
    const float* __restrict__ enc_out, u16* __restrict__ hcP, u16* __restrict__ Abf, int t)
{
    int b = blockIdx.x, tid = threadIdx.x;
    __shared__ __align__(16) float sh[1024];
    __shared__ float red[256];
    __shared__ float dp[128];
    __shared__ float sc[64];
    for (int i = tid; i < 1024; i += 256) sh[i] = hd[b * 1024 + i];
    __syncthreads();
    {
        int a = tid & 127, half = tid >> 7;
        const float* wr = Wd + (size_t)a * 1024 + half * 512;
        const float* hh = sh + half * 512;
        float s = 0.0f;
        for (int k = 0; k < 512; k += 4) {
            f32x4 w4 = *(const f32x4*)(wr + k);
            f32x4 h4 = *(const f32x4*)(hh + k);
            s += w4.x * h4.x + w4.y * h4.y + w4.z * h4.z + w4.w * h4.w;
        }
        red[tid] = s;
    }
    __syncthreads();
    if (tid < 128) dp[tid] = red[tid] + red[tid + 128] + bd[tid];
    __syncthreads();
    {
        int si = tid >> 2, q = tid & 3;
        const float* ep = eproj + ((size_t)b * 64 + si) * 128 + q * 32;
        float s = 0.0f;
#pragma unroll 8
        for (int a = 0; a < 32; ++a) s += v_att[q * 32 + a] * tanhf(dp[q * 32 + a] + ep[a]);
        red[tid] = s;
    }
    __syncthreads();
    if (tid < 64)
        sc[tid] = red[tid * 4] + red[tid * 4 + 1] + red[tid * 4 + 2] + red[tid * 4 + 3] + bv[0];
    __syncthreads();
    if (tid < 64) {
        float x = sc[tid], mx = x;
#pragma unroll
        for (int off = 32; off; off >>= 1) mx = fmaxf(mx, __shfl_xor(mx, off));
        float e = expf(x - mx), ssum = e;
#pragma unroll
        for (int off = 32; off; off >>= 1) ssum += __shfl_xor(ssum, off);
        sc[tid] = e / ssum;
    }
    __syncthreads();
    float c0 = 0, c1 = 0, c2 = 0, c3 = 0;
    const float* eo = enc_out + (size_t)b * 64 * 1024;
    for (int s2 = 0; s2 < 64; ++s2) {
        float wv = sc[s2];
        const float* rowp = eo + s2 * 1024;
        c0 += wv * rowp[tid];       c1 += wv * rowp[tid + 256];
        c2 += wv * rowp[tid + 512]; c3 += wv * rowp[tid + 768];
    }
    u16 v0 = f2bf(c0), v1 = f2bf(c1), v2 = f2bf(c2), v3 = f2bf(c3);
    u16* ar = Abf + ((size_t)t * 32 + b) * 2048 + 1024;
    ar[tid] = v0; ar[tid + 256] = v1; ar[tid + 512] = v2; ar[tid + 768] = v3;
    u16* hr = hcP + (size_t)b * 2048 + 1024;
    hr[tid] = v0; hr[tid + 256] = v1; hr[tid + 512] = v2; hr[tid + 768] = v3;
}

// ---------------- host ----------------
extern "C" void kernel_launch(void* const* d_in, const int* in_sizes, int n_in,
                              void* d_out, int out_size, void* d_ws, size_t ws_size,
                              hipStream_t stream)
{
    (void)in_sizes; (void)n_in; (void)out_size; (void)ws_size;
    const int*   src     = (const int*)d_in[0];
    const int*   tgt     = (const int*)d_in[1];
    const float* enc_emb = (const float*)d_in[2];
    const float* eWih_f  = (const float*)d_in[3];
    const float* eWhh_f  = (const float*)d_in[4];
    const float* ebih_f  = (const float*)d_in[5];
    const float* ebhh_f  = (const float*)d_in[6];
    const float* eWih_b  = (const float*)d_in[7];
    const float* eWhh_b  = (const float*)d_in[8];
    const float* ebih_b  = (const float*)d_in[9];
    const float* ebhh_b  = (const float*)d_in[10];
    const float* dec_emb = (const float*)d_in[11];
    const float* Wd      = (const float*)d_in[12];
    const float* bd      = (const float*)d_in[13];
    const float* We      = (const float*)d_in[14];
    const float* be      = (const float*)d_in[15];
    const float* v_att   = (const float*)d_in[16];
    const float* bv      = (const float*)d_in[17];
    const float* dWih    = (const float*)d_in[18];
    const float* dWhh    = (const float*)d_in[19];
    const float* dbih    = (const float*)d_in[20];
    const float* dbhh    = (const float*)d_in[21];
    const float* Wo      = (const float*)d_in[22];
    const float* bo      = (const float*)d_in[23];
    float* out = (float*)d_out;

    char* wp = (char*)d_ws;
    auto alloc = [&](size_t nbytes) -> void* {
        void* p = (void*)wp;
        wp += (nbytes + 255) & ~(size_t)255;
        return p;
    };
    u16*   Xe_bf   = (u16*)alloc(2048u * 256 * 2);
    u16*   Ed_bf   = (u16*)alloc(2048u * 256 * 2);
    float* Gf_p    = (float*)alloc(2048u * 2048 * 4);
    float* Gb_p    = (float*)alloc(2048u * 2048 * 4);
    float* Pre_p   = (float*)alloc(2048u * 4096 * 4);
    float* cf      = (float*)alloc(16384u * 4);       // contiguous zero region start
    float* cbu     = (float*)alloc(16384u * 4);
    u16*   hbf     = (u16*)alloc(2u * 2 * 16384 * 2); // [pp][dir][32*512]
    float* enc_out = (float*)alloc(2048u * 1024 * 4);
    u16*   enc_bf  = (u16*)alloc(2048u * 1024 * 2);
    float* eproj   = (float*)alloc(2048u * 128 * 4);
    float* hd0     = (float*)alloc(32768u * 4);
    float* hd1     = (float*)alloc(32768u * 4);
    float* hd[2]   = { hd0, hd1 };
    float* cd      = (float*)alloc(32768u * 4);
    u16*   hc      = (u16*)alloc(2u * 32 * 2048 * 2); // [pp][32][2048]
    u16*   Abf     = (u16*)alloc(2048u * 2048 * 2);
    u16*   Wbf     = (u16*)alloc(32000u * 2048 * 2);
    u16*   W2      = (u16*)alloc(4096u * 2048 * 2);
    u16*   Wencf   = (u16*)alloc(2048u * 512 * 2);
    u16*   Wencb   = (u16*)alloc(2048u * 512 * 2);
    u16*   Wembf   = (u16*)alloc(2048u * 256 * 2);
    u16*   Wembb   = (u16*)alloc(2048u * 256 * 2);
    u16*   Wembd   = (u16*)alloc(4096u * 256 * 2);
    u16*   We_bf   = (u16*)alloc(128u * 1024 * 2);

    // zero cf, cb, hbf (contiguous: 16384+16384+32768 f32-equivalents = 65536 f32)
    k_zero<<<256, 256, 0, stream>>>(cf, 65536);

    // weight prep
    k_cast_bf16<<<32000, 256, 0, stream>>>(Wo, Wbf, 8192000);
    k_cast_bf16<<<64,    256, 0, stream>>>(We, We_bf, 16384);
    k_prep_perm<<<1024, 256, 0, stream>>>(eWhh_f, Wencf, 512, 128, 512, 0, 262144);
    k_prep_perm<<<1024, 256, 0, stream>>>(eWhh_b, Wencb, 512, 128, 512, 0, 262144);
    k_prep_perm<<<512,  256, 0, stream>>>(eWih_f, Wembf, 512, 64, 256, 0, 131072);
    k_prep_perm<<<512,  256, 0, stream>>>(eWih_b, Wembb, 512, 64, 256, 0, 131072);
    k_prep_perm<<<1024, 256, 0, stream>>>(dWih, Wembd, 1024, 64, 1280, 0, 262144);
    k_prep_w2<<<8192, 256, 0, stream>>>(dWhh, dWih, W2);

    k_embed_bf<<<512, 256, 0, stream>>>(src, enc_emb, Xe_bf);
    k_embed_bf<<<512, 256, 0, stream>>>(tgt, dec_emb, Ed_bf);

    // input projections (gate-interleaved outputs, biases folded)
    k_gemm_bf<<<256, 256, 0, stream>>>(Xe_bf, Wembf, 256, ebih_f, ebhh_f, 512,
                                       Gf_p, 2048, 16, 16, 0, 1);
    k_gemm_bf<<<256, 256, 0, stream>>>(Xe_bf, Wembb, 256, ebih_b, ebhh_b, 512,
                                       Gb_p, 2048, 16, 16, 0, 1);
    k_gemm_bf<<<512, 256, 0, stream>>>(Ed_bf, Wembd, 256, dbih, dbhh, 1024,
                                       Pre_p, 4096, 16, 32, 0, 1);

    // encoder scan
    for (int s = 0; s < 64; ++s) {
        u16* hA = hbf + (s & 1) * 32768;
        u16* hB = hbf + (1 - (s & 1)) * 32768;
        k_enc_step2<<<128, 256, 0, stream>>>(Wencf, Wencb, Gf_p, Gb_p, hA, hB,
                                             cf, cbu, enc_out, enc_bf, s);
    }

    // enc_proj + decoder init
    k_gemm_bf<<<16, 256, 0, stream>>>(enc_bf, We_bf, 1024, be, nullptr, 0,
                                      eproj, 128, 16, 1, 0, 1);
    k_dec_init<<<128, 256, 0, stream>>>(enc_out, cf, cbu, hd[0], cd, hc);

    // decoder scan
    for (int t = 0; t < 64; ++t) {
        int p = t & 1;
        k_attn<<<32, 256, 0, stream>>>(hd[p], Wd, bd, eproj, v_att, bv, enc_out,
                                       hc + p * 65536, Abf, t);
        k_dec_step<<<128, 256, 0, stream>>>(W2, Pre_p, hc + p * 65536, hc + (1 - p) * 65536,
                                            hd[1 - p], cd, Abf, t);
    }

    // logits: [2048,2048] @ [32000,2048]^T, row remap (t,b)->(b,t)
    k_gemm_bf<<<4000, 256, 0, stream>>>(Abf, Wbf, 2048, bo, nullptr, 0,
                                        out, 32000, 16, 250, 1, 1);
}